// Round 3
// baseline (8445.418 us; speedup 1.0000x reference)
//
#include <hip/hip_runtime.h>

typedef _Float16 f16x8 __attribute__((ext_vector_type(8)));
typedef float    f32x16 __attribute__((ext_vector_type(16)));

#define BATCH   262144
#define LATENT  100
#define HDIM    64
#define SEQ_LEN 30
#define DT      0.03f

__device__ __forceinline__ float sigm(float x) {
    return __fdividef(1.0f, 1.0f + __expf(-x));
}
__device__ __forceinline__ float tanh_f(float x) {
    float ax = fabsf(x);
    float e  = __expf(-2.0f * ax);
    return copysignf(__fdividef(1.0f - e, 1.0f + e), x);
}
__device__ __forceinline__ float hsum8(f16x8 v) {
    // pairwise f16 tree, finish in f32 (6 VALU)
    _Float16 a0 = (_Float16)(v[0] + v[4]);
    _Float16 a1 = (_Float16)(v[1] + v[5]);
    _Float16 a2 = (_Float16)(v[2] + v[6]);
    _Float16 a3 = (_Float16)(v[3] + v[7]);
    return ((float)(_Float16)(a0 + a2)) + ((float)(_Float16)(a1 + a3));
}
__device__ __forceinline__ float fold4(const float* __restrict__ W, int row,
                                       float4 s, float a) {
    a = fmaf(W[row * 4 + 0], s.x, a);
    a = fmaf(W[row * 4 + 1], s.y, a);
    a = fmaf(W[row * 4 + 2], s.z, a);
    a = fmaf(W[row * 4 + 3], s.w, a);
    return a;
}

// ws layout (float units):
//   [0, 256)      beff[256]        (W_ih@b_emb + b_ih + b_hh), f32
//   [256, 1280)   Weff[256][4]     (W_ih @ W_emb), f32
//   [1280, 9472)  w2h: W_hh as _Float16 [256 rows][64 k]  (byte ofs 5120, 16B aligned)
__global__ void prep_kernel(const float* __restrict__ W_emb,
                            const float* __restrict__ b_emb,
                            const float* __restrict__ W_ih,
                            const float* __restrict__ b_ih,
                            const float* __restrict__ b_hh,
                            const float* __restrict__ W_hh,
                            float* __restrict__ ws) {
    int r = threadIdx.x;  // 0..255
    float a0 = 0.f, a1 = 0.f, a2 = 0.f, a3 = 0.f;
    float bb = b_ih[r] + b_hh[r];
    for (int k = 0; k < HDIM; ++k) {
        float w = W_ih[r * HDIM + k];
        a0 = fmaf(w, W_emb[k * 4 + 0], a0);
        a1 = fmaf(w, W_emb[k * 4 + 1], a1);
        a2 = fmaf(w, W_emb[k * 4 + 2], a2);
        a3 = fmaf(w, W_emb[k * 4 + 3], a3);
        bb = fmaf(w, b_emb[k], bb);
    }
    ws[r] = bb;
    ws[256 + r * 4 + 0] = a0; ws[256 + r * 4 + 1] = a1;
    ws[256 + r * 4 + 2] = a2; ws[256 + r * 4 + 3] = a3;
    _Float16* w2h = (_Float16*)(ws + 1280);
    for (int k = 0; k < HDIM; ++k)
        w2h[r * HDIM + k] = (_Float16)W_hh[r * HDIM + k];
}

__launch_bounds__(256, 2)
__global__ void rollout_kernel(const float* __restrict__ z,
                               const float* __restrict__ init_state,
                               const float* __restrict__ W_ctrl,
                               const float* __restrict__ b_ctrl,
                               const float* __restrict__ W_init,
                               const float* __restrict__ b_init,
                               const float* __restrict__ ws,
                               float* __restrict__ out) {
    const int b = blockIdx.x * 256 + threadIdx.x;

    const float*    __restrict__ beff = ws;
    const float*    __restrict__ Weff = ws + 256;
    const _Float16* __restrict__ w2h  = (const _Float16*)(ws + 1280);

    // ---- c0 = h0 = z @ W_init.T + b_init (f32, vector vars only) ----
    f32x16 cA, cB, cC, cD;
    #pragma unroll
    for (int i = 0; i < 16; ++i) {
        cA[i] = b_init[i];      cB[i] = b_init[16 + i];
        cC[i] = b_init[32 + i]; cD[i] = b_init[48 + i];
    }
    const float4* z4 = (const float4*)z;
    #pragma unroll 1
    for (int kk = 0; kk < LATENT / 4; ++kk) {
        float4 zv = z4[(size_t)b * (LATENT / 4) + kk];
        int k0 = kk * 4;
#define INIT16(CV, JB)                                                        \
        { _Pragma("unroll")                                                   \
          for (int i = 0; i < 16; ++i) {                                      \
              const float* wr = W_init + ((JB) + i) * LATENT + k0;            \
              float a = CV[i];                                                \
              a = fmaf(zv.x, wr[0], a);                                       \
              a = fmaf(zv.y, wr[1], a);                                       \
              a = fmaf(zv.z, wr[2], a);                                       \
              a = fmaf(zv.w, wr[3], a);                                       \
              CV[i] = a; } }
        INIT16(cA, 0) INIT16(cB, 16) INIT16(cC, 32) INIT16(cD, 48)
#undef INIT16
    }

    f16x8 h0v, h1v, h2v, h3v, h4v, h5v, h6v, h7v;
#define PACKH(HV, CV, B) { _Pragma("unroll") \
    for (int i = 0; i < 8; ++i) HV[i] = (_Float16)CV[(B) + i]; }
    PACKH(h0v, cA, 0) PACKH(h1v, cA, 8) PACKH(h2v, cB, 0) PACKH(h3v, cB, 8)
    PACKH(h4v, cC, 0) PACKH(h5v, cC, 8) PACKH(h6v, cD, 0) PACKH(h7v, cD, 8)
#undef PACKH

    float4 s = ((const float4*)init_state)[b];
    float4* out4 = (float4*)out;
    const float bc0 = b_ctrl[0], bc1 = b_ctrl[1];
    const float* __restrict__ Wc0 = W_ctrl;
    const float* __restrict__ Wc1 = W_ctrl + 64;

#define DOT8(ACC, WP, HV, IDX) ACC = __builtin_elementwise_fma((WP)[IDX], HV, ACC);
#define DOTROW(ACC, WP) \
    DOT8(ACC, WP, h0v, 0) DOT8(ACC, WP, h1v, 1) DOT8(ACC, WP, h2v, 2) DOT8(ACC, WP, h3v, 3) \
    DOT8(ACC, WP, h4v, 4) DOT8(ACC, WP, h5v, 5) DOT8(ACC, WP, h6v, 6) DOT8(ACC, WP, h7v, 7)

// One pair of hidden units (j0 = J0, J0+1), all literal indices.
#define JP(J0, CV, CI, HN, HL) do {                                           \
    const f16x8* Wi0 = (const f16x8*)(w2h + (size_t)(      (J0)    ) * 64);   \
    const f16x8* Wi1 = (const f16x8*)(w2h + (size_t)(      (J0) + 1) * 64);   \
    const f16x8* Wf0 = (const f16x8*)(w2h + (size_t)( 64 + (J0)    ) * 64);   \
    const f16x8* Wf1 = (const f16x8*)(w2h + (size_t)( 64 + (J0) + 1) * 64);   \
    const f16x8* Wg0 = (const f16x8*)(w2h + (size_t)(128 + (J0)    ) * 64);   \
    const f16x8* Wg1 = (const f16x8*)(w2h + (size_t)(128 + (J0) + 1) * 64);   \
    const f16x8* Wo0 = (const f16x8*)(w2h + (size_t)(192 + (J0)    ) * 64);   \
    const f16x8* Wo1 = (const f16x8*)(w2h + (size_t)(192 + (J0) + 1) * 64);   \
    f16x8 ai0 = {0,0,0,0,0,0,0,0}, af0 = {0,0,0,0,0,0,0,0};                   \
    f16x8 ag0 = {0,0,0,0,0,0,0,0}, ao0 = {0,0,0,0,0,0,0,0};                   \
    f16x8 ai1 = {0,0,0,0,0,0,0,0}, af1 = {0,0,0,0,0,0,0,0};                   \
    f16x8 ag1 = {0,0,0,0,0,0,0,0}, ao1 = {0,0,0,0,0,0,0,0};                   \
    DOTROW(ai0, Wi0) DOTROW(af0, Wf0) DOTROW(ag0, Wg0) DOTROW(ao0, Wo0)       \
    DOTROW(ai1, Wi1) DOTROW(af1, Wf1) DOTROW(ag1, Wg1) DOTROW(ao1, Wo1)       \
    float pi0 = fold4(Weff,       (J0),     s, hsum8(ai0) + beff[      (J0)    ]); \
    float pf0 = fold4(Weff,  64 + (J0),     s, hsum8(af0) + beff[ 64 + (J0)    ]); \
    float pg0 = fold4(Weff, 128 + (J0),     s, hsum8(ag0) + beff[128 + (J0)    ]); \
    float po0 = fold4(Weff, 192 + (J0),     s, hsum8(ao0) + beff[192 + (J0)    ]); \
    float pi1 = fold4(Weff,       (J0) + 1, s, hsum8(ai1) + beff[      (J0) + 1]); \
    float pf1 = fold4(Weff,  64 + (J0) + 1, s, hsum8(af1) + beff[ 64 + (J0) + 1]); \
    float pg1 = fold4(Weff, 128 + (J0) + 1, s, hsum8(ag1) + beff[128 + (J0) + 1]); \
    float po1 = fold4(Weff, 192 + (J0) + 1, s, hsum8(ao1) + beff[192 + (J0) + 1]); \
    float ig0 = sigm(pi0), fg0 = sigm(pf0), gg0 = tanh_f(pg0), og0 = sigm(po0);    \
    float ig1 = sigm(pi1), fg1 = sigm(pf1), gg1 = tanh_f(pg1), og1 = sigm(po1);    \
    float c0_ = fmaf(fg0, CV[(CI)],     ig0 * gg0); CV[(CI)]     = c0_;       \
    float c1_ = fmaf(fg1, CV[(CI) + 1], ig1 * gg1); CV[(CI) + 1] = c1_;       \
    float hn0_ = og0 * tanh_f(c0_);                                           \
    float hn1_ = og1 * tanh_f(c1_);                                           \
    ped_ = fmaf(Wc0[(J0)], hn0_, ped_); ped_ = fmaf(Wc0[(J0) + 1], hn1_, ped_); \
    str_ = fmaf(Wc1[(J0)], hn0_, str_); str_ = fmaf(Wc1[(J0) + 1], hn1_, str_); \
    HN[(HL)]     = (_Float16)hn0_;                                            \
    HN[(HL) + 1] = (_Float16)hn1_;                                            \
} while (0);

    #pragma unroll 1
    for (int t = 0; t < SEQ_LEN; ++t) {
        f16x8 h0n, h1n, h2n, h3n, h4n, h5n, h6n, h7n;
        float ped_ = bc0, str_ = bc1;

        JP( 0, cA,  0, h0n, 0) JP( 2, cA,  2, h0n, 2) JP( 4, cA,  4, h0n, 4) JP( 6, cA,  6, h0n, 6)
        JP( 8, cA,  8, h1n, 0) JP(10, cA, 10, h1n, 2) JP(12, cA, 12, h1n, 4) JP(14, cA, 14, h1n, 6)
        JP(16, cB,  0, h2n, 0) JP(18, cB,  2, h2n, 2) JP(20, cB,  4, h2n, 4) JP(22, cB,  6, h2n, 6)
        JP(24, cB,  8, h3n, 0) JP(26, cB, 10, h3n, 2) JP(28, cB, 12, h3n, 4) JP(30, cB, 14, h3n, 6)
        JP(32, cC,  0, h4n, 0) JP(34, cC,  2, h4n, 2) JP(36, cC,  4, h4n, 4) JP(38, cC,  6, h4n, 6)
        JP(40, cC,  8, h5n, 0) JP(42, cC, 10, h5n, 2) JP(44, cC, 12, h5n, 4) JP(46, cC, 14, h5n, 6)
        JP(48, cD,  0, h6n, 0) JP(50, cD,  2, h6n, 2) JP(52, cD,  4, h6n, 4) JP(54, cD,  6, h6n, 6)
        JP(56, cD,  8, h7n, 0) JP(58, cD, 10, h7n, 2) JP(60, cD, 12, h7n, 4) JP(62, cD, 14, h7n, 6)

        h0v = h0n; h1v = h1n; h2v = h2n; h3v = h3n;
        h4v = h4n; h5v = h5n; h6v = h6n; h7v = h7n;

        // ---- plant (uses OLD s.z / s.w where required) ----
        float beta = fminf(0.5f, fmaxf(-0.5f, str_));
        float v1   = fminf(10.0f, fmaxf(0.0f, fmaf(ped_, DT, s.w)));
        float cpsi = __cosf(s.z);
        float spsi = __sinf(s.z);
        float tb   = __fdividef(__sinf(beta), __cosf(beta));
        float psid = fminf(1.57f, fmaxf(-1.57f, s.w * tb * 0.4f));
        s.x = fmaf(v1 * cpsi, DT, s.x);
        s.y = fmaf(v1 * spsi, DT, s.y);
        s.z = fmaf(psid, DT, s.z);
        s.w = v1;

        out4[(size_t)b * SEQ_LEN + t] = s;
    }
#undef JP
#undef DOTROW
#undef DOT8
}

extern "C" void kernel_launch(void* const* d_in, const int* in_sizes, int n_in,
                              void* d_out, int out_size, void* d_ws, size_t ws_size,
                              hipStream_t stream) {
    const float* z          = (const float*)d_in[0];
    const float* init_state = (const float*)d_in[1];
    const float* W_emb      = (const float*)d_in[2];
    const float* b_emb      = (const float*)d_in[3];
    const float* W_ih       = (const float*)d_in[4];
    const float* W_hh       = (const float*)d_in[5];
    const float* b_ih       = (const float*)d_in[6];
    const float* b_hh       = (const float*)d_in[7];
    const float* W_ctrl     = (const float*)d_in[8];
    const float* b_ctrl     = (const float*)d_in[9];
    const float* W_init     = (const float*)d_in[10];
    const float* b_init     = (const float*)d_in[11];
    float* out = (float*)d_out;
    float* ws  = (float*)d_ws;

    prep_kernel<<<1, 256, 0, stream>>>(W_emb, b_emb, W_ih, b_ih, b_hh, W_hh, ws);
    rollout_kernel<<<BATCH / 256, 256, 0, stream>>>(
        z, init_state, W_ctrl, b_ctrl, W_init, b_init, ws, out);
}

// Round 4
// 2308.717 us; speedup vs baseline: 3.6581x; 3.6581x over previous
//
#include <hip/hip_runtime.h>

typedef _Float16 f16;
typedef _Float16 h8  __attribute__((ext_vector_type(8)));
typedef float    fx16 __attribute__((ext_vector_type(16)));

#define BATCH   262144
#define SEQ_LEN 30
#define DT      0.03f

__device__ __forceinline__ float sigm(float x) {
    return __fdividef(1.0f, 1.0f + __expf(-x));
}
__device__ __forceinline__ float tanh_f(float x) {
    float e = __expf(-2.0f * fabsf(x));
    return copysignf(__fdividef(1.0f - e, 1.0f + e), x);
}
__device__ __forceinline__ float hsum8(h8 v) {
    _Float16 a0 = (_Float16)(v[0] + v[4]);
    _Float16 a1 = (_Float16)(v[1] + v[5]);
    _Float16 a2 = (_Float16)(v[2] + v[6]);
    _Float16 a3 = (_Float16)(v[3] + v[7]);
    return ((float)(_Float16)(a0 + a2)) + ((float)(_Float16)(a1 + a3));
}

// ws image (f16 units):
//   [0, 20480)       WMAIN: 40 frags (ct 0..7, kk 0..4) x 64 lanes x 8 elems
//                    value = B[k][n], n = ct*32+(l&31), k = kk*16+(l>>5)*8+e
//                    k<64: W_hh[n][k]; 64-67: Weff[n][k-64]; 68-71: Weff[n][k-68];
//                    72: beff[n]; else 0
//   [20480, 20608)   WCTRL: [0..63]=W_ctrl[0][u], [64..127]=W_ctrl[1][u]
__global__ void prep_kernel(const float* __restrict__ W_emb,
                            const float* __restrict__ b_emb,
                            const float* __restrict__ W_ih,
                            const float* __restrict__ b_ih,
                            const float* __restrict__ b_hh,
                            const float* __restrict__ W_hh,
                            const float* __restrict__ W_ctrl,
                            f16* __restrict__ wsh) {
    __shared__ float weff_s[256][4];
    __shared__ float beff_s[256];
    {
        int r = threadIdx.x;
        float a0 = 0.f, a1 = 0.f, a2 = 0.f, a3 = 0.f;
        float bb = b_ih[r] + b_hh[r];
        for (int k = 0; k < 64; ++k) {
            float w = W_ih[r * 64 + k];
            a0 = fmaf(w, W_emb[k * 4 + 0], a0);
            a1 = fmaf(w, W_emb[k * 4 + 1], a1);
            a2 = fmaf(w, W_emb[k * 4 + 2], a2);
            a3 = fmaf(w, W_emb[k * 4 + 3], a3);
            bb = fmaf(w, b_emb[k], bb);
        }
        weff_s[r][0] = a0; weff_s[r][1] = a1;
        weff_s[r][2] = a2; weff_s[r][3] = a3;
        beff_s[r] = bb;
    }
    __syncthreads();
    for (int idx = threadIdx.x; idx < 40 * 512; idx += 256) {
        int frag = idx >> 9, rem = idx & 511;
        int l = rem >> 3, e = rem & 7;
        int ct = frag / 5, kk = frag % 5;
        int n = ct * 32 + (l & 31);
        int k = kk * 16 + (l >> 5) * 8 + e;
        float v;
        if      (k < 64)  v = W_hh[n * 64 + k];
        else if (k < 68)  v = weff_s[n][k - 64];
        else if (k < 72)  v = weff_s[n][k - 68];
        else if (k == 72) v = beff_s[n];
        else              v = 0.0f;
        wsh[idx] = (f16)v;
    }
    if (threadIdx.x < 128) wsh[20480 + threadIdx.x] = (f16)W_ctrl[threadIdx.x];
}

__launch_bounds__(256, 2)
__global__ void rollout_kernel(const float* __restrict__ z,
                               const float* __restrict__ init_state,
                               const float* __restrict__ W_init,
                               const float* __restrict__ b_init,
                               const float* __restrict__ b_ctrl,
                               const f16* __restrict__ wsh,
                               float* __restrict__ out) {
    __shared__ __align__(16) f16 wmain[20480];          // 40 KB
    __shared__ __align__(16) f16 wctrl[128];
    __shared__ __align__(16) f16 htile[4][2048];        // 4 KB per wave

    const int tid    = threadIdx.x;
    const int lane   = tid & 63;
    const int wv     = tid >> 6;
    const int lrow   = lane & 31;    // A-operand row / D-col index
    const int hi     = lane >> 5;
    const int rowbase = blockIdx.x * 128 + wv * 32;
    const int lane16 = lane * 16;

    // ---- stage weights to LDS (once) ----
    {
        const uint4* src = (const uint4*)wsh;
        uint4* dst = (uint4*)wmain;
        for (int i = tid; i < 2560; i += 256) dst[i] = src[i];
        if (tid < 16) ((uint4*)wctrl)[tid] = ((const uint4*)(wsh + 20480))[tid];
    }
    __syncthreads();

    char* hb        = (char*)&htile[wv][0];
    const char* wm  = (const char*)wmain;
    const char* wc  = (const char*)wctrl;

    // ---- init: c0 = h0 = z @ W_init^T + b_init via MFMA (K=112, bias at k=100) ----
    fx16 c0v = {}, c1v = {};
    {
        h8 ai[7];
        const float* zr = z + (size_t)(rowbase + lrow) * 100;
        #pragma unroll
        for (int kk = 0; kk < 6; ++kk) {
            const float4 z0 = *(const float4*)(zr + kk * 16 + hi * 8);
            const float4 z1 = *(const float4*)(zr + kk * 16 + hi * 8 + 4);
            h8 av;
            av[0] = (f16)z0.x; av[1] = (f16)z0.y; av[2] = (f16)z0.z; av[3] = (f16)z0.w;
            av[4] = (f16)z1.x; av[5] = (f16)z1.y; av[6] = (f16)z1.z; av[7] = (f16)z1.w;
            ai[kk] = av;
        }
        {
            h8 av = {};
            if (hi == 0) {
                const float4 z0 = *(const float4*)(zr + 96);
                av[0] = (f16)z0.x; av[1] = (f16)z0.y;
                av[2] = (f16)z0.z; av[3] = (f16)z0.w;
                av[4] = (f16)1.0f;   // k=100 -> bias row
            }
            ai[6] = av;
        }
        #pragma unroll
        for (int kk = 0; kk < 7; ++kk) {
            h8 b0, b1;
            int k0 = kk * 16 + hi * 8;
            #pragma unroll
            for (int e = 0; e < 8; ++e) {
                int k = k0 + e;
                float v0 = (k < 100) ? W_init[lrow * 100 + k]
                                     : ((k == 100) ? b_init[lrow] : 0.0f);
                float v1 = (k < 100) ? W_init[(32 + lrow) * 100 + k]
                                     : ((k == 100) ? b_init[32 + lrow] : 0.0f);
                b0[e] = (f16)v0; b1[e] = (f16)v1;
            }
            c0v = __builtin_amdgcn_mfma_f32_32x32x16_f16(ai[kk], b0, c0v, 0, 0, 0);
            c1v = __builtin_amdgcn_mfma_f32_32x32x16_f16(ai[kk], b1, c1v, 0, 0, 0);
        }
        #pragma unroll
        for (int r = 0; r < 16; ++r) {
            int row = (r & 3) + 8 * (r >> 2) + 4 * hi;
            *(f16*)(hb + ((row * 128 + lrow * 2)        ^ ((row & 7) << 4))) = (f16)c0v[r];
            *(f16*)(hb + ((row * 128 + (32 + lrow) * 2) ^ ((row & 7) << 4))) = (f16)c1v[r];
        }
    }

    // ---- per-row plant state (lanes 0..31 own row `lane`) ----
    float sx = 0.f, sy = 0.f, sz = 0.f, sw = 0.f;
    if (lane < 32) {
        float4 s0 = ((const float4*)init_state)[rowbase + lane];
        sx = s0.x; sy = s0.y; sz = s0.z; sw = s0.w;
    }
    const float bc0 = b_ctrl[0], bc1 = b_ctrl[1];

// one group: 4 gate tiles (i,f,g,o) for 32 units, 5 K-steps, then LSTM epilogue
#define GRP(G, CV) do {                                                         \
    fx16 accI = {}, accF = {}, accG = {}, accO = {};                            \
    _Pragma("unroll")                                                           \
    for (int kk = 0; kk < 5; ++kk) {                                            \
        h8 bI = *(const h8*)(wm + (((G) + 0) * 5 + kk) * 1024 + lane16);        \
        h8 bF = *(const h8*)(wm + (((G) + 2) * 5 + kk) * 1024 + lane16);        \
        h8 bG = *(const h8*)(wm + (((G) + 4) * 5 + kk) * 1024 + lane16);        \
        h8 bO = *(const h8*)(wm + (((G) + 6) * 5 + kk) * 1024 + lane16);        \
        accI = __builtin_amdgcn_mfma_f32_32x32x16_f16(af[kk], bI, accI, 0,0,0); \
        accF = __builtin_amdgcn_mfma_f32_32x32x16_f16(af[kk], bF, accF, 0,0,0); \
        accG = __builtin_amdgcn_mfma_f32_32x32x16_f16(af[kk], bG, accG, 0,0,0); \
        accO = __builtin_amdgcn_mfma_f32_32x32x16_f16(af[kk], bO, accO, 0,0,0); \
    }                                                                           \
    _Pragma("unroll")                                                           \
    for (int r = 0; r < 16; ++r) {                                              \
        float ig = sigm(accI[r]);                                               \
        float fg = sigm(accF[r]);                                               \
        float gg = tanh_f(accG[r]);                                             \
        float og = sigm(accO[r]);                                               \
        float cc = fmaf(fg, CV[r], ig * gg);                                    \
        CV[r] = cc;                                                             \
        float hn = og * tanh_f(cc);                                             \
        int row = (r & 3) + 8 * (r >> 2) + 4 * hi;                              \
        *(f16*)(hb + ((row * 128 + ((G) * 32 + lrow) * 2) ^ ((row & 7) << 4)))  \
            = (f16)hn;                                                          \
    }                                                                           \
} while (0)

    for (int t = 0; t < SEQ_LEN; ++t) {
        // A-frags: h(t-1) from LDS + [s_hi|s_lo] / [1|0] tail
        h8 af[5];
        #pragma unroll
        for (int kk = 0; kk < 4; ++kk)
            af[kk] = *(const h8*)(hb + ((lrow * 128 + kk * 32 + hi * 16)
                                        ^ ((lrow & 7) << 4)));
        {
            h8 a4 = {};
            if (lane < 32) {
                f16 hx = (f16)sx, hy = (f16)sy, hz = (f16)sz, hw = (f16)sw;
                a4[0] = hx; a4[1] = hy; a4[2] = hz; a4[3] = hw;
                a4[4] = (f16)(sx - (float)hx);
                a4[5] = (f16)(sy - (float)hy);
                a4[6] = (f16)(sz - (float)hz);
                a4[7] = (f16)(sw - (float)hw);
            } else {
                a4[0] = (f16)1.0f;   // k=72 -> bias row
            }
            af[4] = a4;
        }

        GRP(0, c0v);
        GRP(1, c1v);

        // ---- control + plant (lanes 0..31, row = lane) ----
        if (lane < 32) {
            h8 pv = {}, qv = {};
            #pragma unroll
            for (int j = 0; j < 8; ++j) {
                h8 hv = *(const h8*)(hb + ((lane * 128 + j * 16)
                                           ^ ((lane & 7) << 4)));
                h8 w0 = *(const h8*)(wc + j * 16);
                h8 w1 = *(const h8*)(wc + 128 + j * 16);
                pv = __builtin_elementwise_fma(hv, w0, pv);
                qv = __builtin_elementwise_fma(hv, w1, qv);
            }
            float ped = bc0 + hsum8(pv);
            float str = bc1 + hsum8(qv);

            float beta = fminf(0.5f, fmaxf(-0.5f, str));
            float v1   = fminf(10.0f, fmaxf(0.0f, fmaf(ped, DT, sw)));
            float cpsi = __cosf(sz);
            float spsi = __sinf(sz);
            float tb   = __fdividef(__sinf(beta), __cosf(beta));
            float psid = fminf(1.57f, fmaxf(-1.57f, sw * tb * 0.4f));
            sx = fmaf(v1 * cpsi, DT, sx);
            sy = fmaf(v1 * spsi, DT, sy);
            sz = fmaf(psid, DT, sz);
            sw = v1;

            ((float4*)out)[(size_t)(rowbase + lane) * SEQ_LEN + t]
                = make_float4(sx, sy, sz, sw);
        }
    }
#undef GRP
}

extern "C" void kernel_launch(void* const* d_in, const int* in_sizes, int n_in,
                              void* d_out, int out_size, void* d_ws, size_t ws_size,
                              hipStream_t stream) {
    const float* z          = (const float*)d_in[0];
    const float* init_state = (const float*)d_in[1];
    const float* W_emb      = (const float*)d_in[2];
    const float* b_emb      = (const float*)d_in[3];
    const float* W_ih       = (const float*)d_in[4];
    const float* W_hh       = (const float*)d_in[5];
    const float* b_ih       = (const float*)d_in[6];
    const float* b_hh       = (const float*)d_in[7];
    const float* W_ctrl     = (const float*)d_in[8];
    const float* b_ctrl     = (const float*)d_in[9];
    const float* W_init     = (const float*)d_in[10];
    const float* b_init     = (const float*)d_in[11];
    float* out = (float*)d_out;
    f16*   wsh = (f16*)d_ws;

    prep_kernel<<<1, 256, 0, stream>>>(W_emb, b_emb, W_ih, b_ih, b_hh, W_hh,
                                       W_ctrl, wsh);
    rollout_kernel<<<BATCH / 128, 256, 0, stream>>>(z, init_state, W_init,
                                                    b_init, b_ctrl, wsh, out);
}

// Round 5
// 1386.700 us; speedup vs baseline: 6.0903x; 1.6649x over previous
//
#include <hip/hip_runtime.h>

typedef _Float16 f16;
typedef _Float16 h8  __attribute__((ext_vector_type(8)));
typedef float    fx16 __attribute__((ext_vector_type(16)));

#define BATCH   262144
#define SEQ_LEN 30
#define DT      0.03f

__device__ __forceinline__ float sigm(float x) {
    return __fdividef(1.0f, 1.0f + __expf(-x));
}
__device__ __forceinline__ float tanh_f(float x) {
    float e = __expf(-2.0f * fabsf(x));
    return copysignf(__fdividef(1.0f - e, 1.0f + e), x);
}
__device__ __forceinline__ float hsum8(h8 v) {
    _Float16 a0 = (_Float16)(v[0] + v[4]);
    _Float16 a1 = (_Float16)(v[1] + v[5]);
    _Float16 a2 = (_Float16)(v[2] + v[6]);
    _Float16 a3 = (_Float16)(v[3] + v[7]);
    return ((float)(_Float16)(a0 + a2)) + ((float)(_Float16)(a1 + a3));
}

// wsh image (f16 units):
//  [0, 20480)        WMAIN: frag ((G*4+g)*5+kk) x 64 lanes x 8
//                    n = g*64 + G*32 + (l&31), k = kk*16 + (l>>5)*8 + e
//                    k<64: W_hh[n][k]; 64-67: Weff[n][k-64]; 68-71: Weff[n][k-68];
//                    72: beff[n]; else 0
//  [20480, 27648)    WINIT: frag (G*7+kk2) x 64 x 8
//                    n = G*32+(l&31), k = kk2*16+(l>>5)*8+e
//                    k<100: W_init[n][k]; k==100: b_init[n]; else 0
//  [27648, 27776)    WCTRL
__global__ void prep_kernel(const float* __restrict__ W_emb,
                            const float* __restrict__ b_emb,
                            const float* __restrict__ W_ih,
                            const float* __restrict__ b_ih,
                            const float* __restrict__ b_hh,
                            const float* __restrict__ W_hh,
                            const float* __restrict__ W_ctrl,
                            const float* __restrict__ W_init,
                            const float* __restrict__ b_init,
                            f16* __restrict__ wsh) {
    __shared__ float weff_s[256][4];
    __shared__ float beff_s[256];
    {
        int r = threadIdx.x;
        float a0 = 0.f, a1 = 0.f, a2 = 0.f, a3 = 0.f;
        float bb = b_ih[r] + b_hh[r];
        for (int k = 0; k < 64; ++k) {
            float w = W_ih[r * 64 + k];
            a0 = fmaf(w, W_emb[k * 4 + 0], a0);
            a1 = fmaf(w, W_emb[k * 4 + 1], a1);
            a2 = fmaf(w, W_emb[k * 4 + 2], a2);
            a3 = fmaf(w, W_emb[k * 4 + 3], a3);
            bb = fmaf(w, b_emb[k], bb);
        }
        weff_s[r][0] = a0; weff_s[r][1] = a1;
        weff_s[r][2] = a2; weff_s[r][3] = a3;
        beff_s[r] = bb;
    }
    __syncthreads();
    for (int idx = threadIdx.x; idx < 20480; idx += 256) {
        int frag = idx >> 9, rem = idx & 511;
        int l = rem >> 3, e = rem & 7;
        int G  = frag / 20;
        int g  = (frag / 5) & 3;
        int kk = frag % 5;
        int n = g * 64 + G * 32 + (l & 31);
        int k = kk * 16 + (l >> 5) * 8 + e;
        float v;
        if      (k < 64)  v = W_hh[n * 64 + k];
        else if (k < 68)  v = weff_s[n][k - 64];
        else if (k < 72)  v = weff_s[n][k - 68];
        else if (k == 72) v = beff_s[n];
        else              v = 0.0f;
        wsh[idx] = (f16)v;
    }
    for (int idx = threadIdx.x; idx < 7168; idx += 256) {
        int fr = idx >> 9, rem = idx & 511;
        int l = rem >> 3, e = rem & 7;
        int G = fr / 7, kk2 = fr % 7;
        int n = G * 32 + (l & 31);
        int k = kk2 * 16 + (l >> 5) * 8 + e;
        float v = (k < 100) ? W_init[n * 100 + k]
                            : ((k == 100) ? b_init[n] : 0.0f);
        wsh[20480 + idx] = (f16)v;
    }
    if (threadIdx.x < 128) wsh[27648 + threadIdx.x] = (f16)W_ctrl[threadIdx.x];
}

__launch_bounds__(512, 4)
__global__ void rollout_kernel(const float* __restrict__ z,
                               const float* __restrict__ init_state,
                               const float* __restrict__ b_ctrl,
                               const f16* __restrict__ wsh,
                               float* __restrict__ out) {
    __shared__ __align__(16) f16 wmain[20480];       // 40 KB
    __shared__ __align__(16) f16 htile[4][2048];     // 4 teams x 4 KB
    __shared__ __align__(16) f16 wctrl[128];

    const int tid  = threadIdx.x;
    const int lane = tid & 63;
    const int wv   = tid >> 6;        // 0..7
    const int team = wv >> 1;         // 0..3  (32 batch rows each)
    const int G    = wv & 1;          // unit half: 0 -> units 0..31, 1 -> 32..63
    const int lrow = lane & 31;
    const int hi   = lane >> 5;
    const int rowbase = blockIdx.x * 128 + team * 32;
    const int lane16  = lane * 16;

    {   // stage weights
        const uint4* src = (const uint4*)wsh;
        uint4* dst = (uint4*)wmain;
        for (int i = tid; i < 2560; i += 512) dst[i] = src[i];
        if (tid < 16) ((uint4*)wctrl)[tid] = ((const uint4*)(wsh + 27648))[tid];
    }

    char* hb       = (char*)&htile[team][0];
    const char* wm = (const char*)wmain;
    const char* wc = (const char*)wctrl;

    // ---- init: c0 = h0 = z @ W_init^T + b_init (K=112, bias at k=100) ----
    fx16 cv = {};
    {
        const float* zr   = z + (size_t)(rowbase + lrow) * 100;
        const f16*   wini = wsh + 20480 + G * 7 * 512;
        #pragma unroll
        for (int kk = 0; kk < 6; ++kk) {
            const float4 z0 = *(const float4*)(zr + kk * 16 + hi * 8);
            const float4 z1 = *(const float4*)(zr + kk * 16 + hi * 8 + 4);
            h8 av;
            av[0] = (f16)z0.x; av[1] = (f16)z0.y; av[2] = (f16)z0.z; av[3] = (f16)z0.w;
            av[4] = (f16)z1.x; av[5] = (f16)z1.y; av[6] = (f16)z1.z; av[7] = (f16)z1.w;
            h8 bv = *(const h8*)(wini + kk * 512 + lane * 8);
            cv = __builtin_amdgcn_mfma_f32_32x32x16_f16(av, bv, cv, 0, 0, 0);
        }
        {
            h8 av = {};
            if (hi == 0) {
                const float4 z0 = *(const float4*)(zr + 96);
                av[0] = (f16)z0.x; av[1] = (f16)z0.y;
                av[2] = (f16)z0.z; av[3] = (f16)z0.w;
                av[4] = (f16)1.0f;       // k=100 -> bias
            }
            h8 bv = *(const h8*)(wini + 6 * 512 + lane * 8);
            cv = __builtin_amdgcn_mfma_f32_32x32x16_f16(av, bv, cv, 0, 0, 0);
        }
        #pragma unroll
        for (int r = 0; r < 16; ++r) {
            int row = (r & 3) + 8 * (r >> 2) + 4 * hi;
            *(f16*)(hb + ((row * 128 + (G * 32 + lrow) * 2) ^ ((row & 7) << 4)))
                = (f16)cv[r];
        }
    }

    // plant state: lanes 0..31 of BOTH team waves hold row (rowbase+lane)
    float sx = 0.f, sy = 0.f, sz = 0.f, sw = 0.f;
    if (lane < 32) {
        float4 s0 = ((const float4*)init_state)[rowbase + lane];
        sx = s0.x; sy = s0.y; sz = s0.z; sw = s0.w;
    }
    const float bc0 = b_ctrl[0], bc1 = b_ctrl[1];

    __syncthreads();   // weights staged + h0 visible

    for (int t = 0; t < SEQ_LEN; ++t) {
        // ---- A-frags: h(t-1) + [s_hi|s_lo] / [1|0] tail ----
        h8 af[5];
        #pragma unroll
        for (int kk = 0; kk < 4; ++kk)
            af[kk] = *(const h8*)(hb + ((lrow * 128 + kk * 32 + hi * 16)
                                        ^ ((lrow & 7) << 4)));
        {
            h8 a4 = {};
            if (lane < 32) {
                f16 hx = (f16)sx, hy = (f16)sy, hz = (f16)sz, hw = (f16)sw;
                a4[0] = hx; a4[1] = hy; a4[2] = hz; a4[3] = hw;
                a4[4] = (f16)(sx - (float)hx);
                a4[5] = (f16)(sy - (float)hy);
                a4[6] = (f16)(sz - (float)hz);
                a4[7] = (f16)(sw - (float)hw);
            } else {
                a4[0] = (f16)1.0f;       // k=72 -> bias
            }
            af[4] = a4;
        }
        __syncthreads();   // all reads of h(t-1) done

        // ---- gates for 32 rows x 32 units (this wave's half) ----
        fx16 aI = {}, aF = {}, aG = {}, aO = {};
        #pragma unroll
        for (int kk = 0; kk < 5; ++kk) {
            h8 bI = *(const h8*)(wm + ((G * 4 + 0) * 5 + kk) * 1024 + lane16);
            h8 bF = *(const h8*)(wm + ((G * 4 + 1) * 5 + kk) * 1024 + lane16);
            h8 bG = *(const h8*)(wm + ((G * 4 + 2) * 5 + kk) * 1024 + lane16);
            h8 bO = *(const h8*)(wm + ((G * 4 + 3) * 5 + kk) * 1024 + lane16);
            aI = __builtin_amdgcn_mfma_f32_32x32x16_f16(af[kk], bI, aI, 0, 0, 0);
            aF = __builtin_amdgcn_mfma_f32_32x32x16_f16(af[kk], bF, aF, 0, 0, 0);
            aG = __builtin_amdgcn_mfma_f32_32x32x16_f16(af[kk], bG, aG, 0, 0, 0);
            aO = __builtin_amdgcn_mfma_f32_32x32x16_f16(af[kk], bO, aO, 0, 0, 0);
        }
        #pragma unroll
        for (int r = 0; r < 16; ++r) {
            float ig = sigm(aI[r]);
            float fg = sigm(aF[r]);
            float gg = tanh_f(aG[r]);
            float og = sigm(aO[r]);
            float cc = fmaf(fg, cv[r], ig * gg);
            cv[r] = cc;
            float hn = og * tanh_f(cc);
            int row = (r & 3) + 8 * (r >> 2) + 4 * hi;
            *(f16*)(hb + ((row * 128 + (G * 32 + lrow) * 2) ^ ((row & 7) << 4)))
                = (f16)hn;
        }
        __syncthreads();   // h(t) visible

        // ---- control + plant (lanes 0..31 of both waves; G0 stores) ----
        if (lane < 32) {
            h8 pv = {}, qv = {};
            #pragma unroll
            for (int j = 0; j < 8; ++j) {
                h8 hv = *(const h8*)(hb + ((lane * 128 + j * 16)
                                           ^ ((lane & 7) << 4)));
                h8 w0 = *(const h8*)(wc + j * 16);
                h8 w1 = *(const h8*)(wc + 128 + j * 16);
                pv = __builtin_elementwise_fma(hv, w0, pv);
                qv = __builtin_elementwise_fma(hv, w1, qv);
            }
            float ped = bc0 + hsum8(pv);
            float str = bc1 + hsum8(qv);

            float beta = fminf(0.5f, fmaxf(-0.5f, str));
            float v1   = fminf(10.0f, fmaxf(0.0f, fmaf(ped, DT, sw)));
            float cpsi = __cosf(sz);
            float spsi = __sinf(sz);
            float tb   = __fdividef(__sinf(beta), __cosf(beta));
            float psid = fminf(1.57f, fmaxf(-1.57f, sw * tb * 0.4f));
            sx = fmaf(v1 * cpsi, DT, sx);
            sy = fmaf(v1 * spsi, DT, sy);
            sz = fmaf(psid, DT, sz);
            sw = v1;

            if (G == 0)
                ((float4*)out)[(size_t)(rowbase + lane) * SEQ_LEN + t]
                    = make_float4(sx, sy, sz, sw);
        }
    }
}

extern "C" void kernel_launch(void* const* d_in, const int* in_sizes, int n_in,
                              void* d_out, int out_size, void* d_ws, size_t ws_size,
                              hipStream_t stream) {
    const float* z          = (const float*)d_in[0];
    const float* init_state = (const float*)d_in[1];
    const float* W_emb      = (const float*)d_in[2];
    const float* b_emb      = (const float*)d_in[3];
    const float* W_ih       = (const float*)d_in[4];
    const float* W_hh       = (const float*)d_in[5];
    const float* b_ih       = (const float*)d_in[6];
    const float* b_hh       = (const float*)d_in[7];
    const float* W_ctrl     = (const float*)d_in[8];
    const float* b_ctrl     = (const float*)d_in[9];
    const float* W_init     = (const float*)d_in[10];
    const float* b_init     = (const float*)d_in[11];
    float* out = (float*)d_out;
    f16*   wsh = (f16*)d_ws;

    prep_kernel<<<1, 256, 0, stream>>>(W_emb, b_emb, W_ih, b_ih, b_hh, W_hh,
                                       W_ctrl, W_init, b_init, wsh);
    rollout_kernel<<<BATCH / 128, 512, 0, stream>>>(z, init_state, b_ctrl,
                                                    wsh, out);
}

// Round 6
// 730.476 us; speedup vs baseline: 11.5615x; 1.8984x over previous
//
#include <hip/hip_runtime.h>

typedef _Float16 f16;
typedef _Float16 h8  __attribute__((ext_vector_type(8)));
typedef float    fx16 __attribute__((ext_vector_type(16)));

#define BATCH   262144
#define SEQ_LEN 30
#define DT      0.03f
#define N2LOG2E (-2.8853900817779268f)

__device__ __forceinline__ float rcpf(float x) { return __builtin_amdgcn_rcpf(x); }
__device__ __forceinline__ float ex2(float x)  { return __builtin_amdgcn_exp2f(x); }
__device__ __forceinline__ float hsum8(h8 v) {
    _Float16 a0 = (_Float16)(v[0] + v[4]);
    _Float16 a1 = (_Float16)(v[1] + v[5]);
    _Float16 a2 = (_Float16)(v[2] + v[6]);
    _Float16 a3 = (_Float16)(v[3] + v[7]);
    return ((float)(_Float16)(a0 + a2)) + ((float)(_Float16)(a1 + a3));
}

// wsh image (f16 units):
//  [0, 20480)     WMAIN frag ((G*4+g)*5+kk) x 64 lanes x 8:
//                 n = g*64 + G*32 + (l&31), k = kk*16 + (l>>5)*8 + e
//                 k<64: W_hh[n][k]*sc; 64-67: Weff[n][k-64]*sc; 68: beff[n]*sc; else 0
//                 sc = -log2(e) for gates i,f,o; -2*log2(e) for gate g
//  [20480, 27648) WINIT frag (G*7+kk2) x 64 x 8 (unscaled)
//  [27648, 27776) WCTRL
__global__ void prep_kernel(const float* __restrict__ W_emb,
                            const float* __restrict__ b_emb,
                            const float* __restrict__ W_ih,
                            const float* __restrict__ b_ih,
                            const float* __restrict__ b_hh,
                            const float* __restrict__ W_hh,
                            const float* __restrict__ W_ctrl,
                            const float* __restrict__ W_init,
                            const float* __restrict__ b_init,
                            f16* __restrict__ wsh) {
    __shared__ float weff_s[256][4];
    __shared__ float beff_s[256];
    {
        int r = threadIdx.x;
        float a0 = 0.f, a1 = 0.f, a2 = 0.f, a3 = 0.f;
        float bb = b_ih[r] + b_hh[r];
        for (int k = 0; k < 64; ++k) {
            float w = W_ih[r * 64 + k];
            a0 = fmaf(w, W_emb[k * 4 + 0], a0);
            a1 = fmaf(w, W_emb[k * 4 + 1], a1);
            a2 = fmaf(w, W_emb[k * 4 + 2], a2);
            a3 = fmaf(w, W_emb[k * 4 + 3], a3);
            bb = fmaf(w, b_emb[k], bb);
        }
        weff_s[r][0] = a0; weff_s[r][1] = a1;
        weff_s[r][2] = a2; weff_s[r][3] = a3;
        beff_s[r] = bb;
    }
    __syncthreads();
    for (int idx = threadIdx.x; idx < 20480; idx += 256) {
        int frag = idx >> 9, rem = idx & 511;
        int l = rem >> 3, e = rem & 7;
        int G  = frag / 20;
        int g  = (frag / 5) & 3;
        int kk = frag % 5;
        int n = g * 64 + G * 32 + (l & 31);
        int k = kk * 16 + (l >> 5) * 8 + e;
        float sc = (g == 2) ? -2.8853900817779268f : -1.4426950408889634f;
        float v;
        if      (k < 64)  v = W_hh[n * 64 + k];
        else if (k < 68)  v = weff_s[n][k - 64];
        else if (k == 68) v = beff_s[n];
        else              v = 0.0f;
        wsh[idx] = (f16)(v * sc);
    }
    for (int idx = threadIdx.x; idx < 7168; idx += 256) {
        int fr = idx >> 9, rem = idx & 511;
        int l = rem >> 3, e = rem & 7;
        int G = fr / 7, kk2 = fr % 7;
        int n = G * 32 + (l & 31);
        int k = kk2 * 16 + (l >> 5) * 8 + e;
        float v = (k < 100) ? W_init[n * 100 + k]
                            : ((k == 100) ? b_init[n] : 0.0f);
        wsh[20480 + idx] = (f16)v;
    }
    if (threadIdx.x < 128) wsh[27648 + threadIdx.x] = (f16)W_ctrl[threadIdx.x];
}

__launch_bounds__(512, 4)
__global__ void rollout_kernel(const float* __restrict__ z,
                               const float* __restrict__ init_state,
                               const float* __restrict__ b_ctrl,
                               const f16* __restrict__ wsh,
                               float* __restrict__ out) {
    __shared__ __align__(16) f16 wmain[20480];       // 40 KB
    __shared__ __align__(16) f16 htile[2][4][2048];  // ping-pong, 32 KB
    __shared__ __align__(16) f16 wctrl[128];

    const int tid  = threadIdx.x;
    const int lane = tid & 63;
    const int wv   = tid >> 6;
    const int team = wv >> 1;
    const int G    = wv & 1;
    const int lrow = lane & 31;
    const int hi   = lane >> 5;
    const int rowbase = blockIdx.x * 128 + team * 32;
    const int lane16  = lane * 16;

    {   // stage weights
        const uint4* src = (const uint4*)wsh;
        uint4* dst = (uint4*)wmain;
        for (int i = tid; i < 2560; i += 512) dst[i] = src[i];
        if (tid < 16) ((uint4*)wctrl)[tid] = ((const uint4*)(wsh + 27648))[tid];
    }

    char* hb0      = (char*)&htile[0][team][0];
    char* hb1      = (char*)&htile[1][team][0];
    const char* wm = (const char*)wmain;
    const char* wc = (const char*)wctrl;

    // ---- init: c0 = h0 = z @ W_init^T + b_init (K=112, bias at k=100) ----
    fx16 cv = {};
    {
        const float* zr   = z + (size_t)(rowbase + lrow) * 100;
        const f16*   wini = wsh + 20480 + G * 7 * 512;
        #pragma unroll
        for (int kk = 0; kk < 6; ++kk) {
            const float4 z0 = *(const float4*)(zr + kk * 16 + hi * 8);
            const float4 z1 = *(const float4*)(zr + kk * 16 + hi * 8 + 4);
            h8 av;
            av[0] = (f16)z0.x; av[1] = (f16)z0.y; av[2] = (f16)z0.z; av[3] = (f16)z0.w;
            av[4] = (f16)z1.x; av[5] = (f16)z1.y; av[6] = (f16)z1.z; av[7] = (f16)z1.w;
            h8 bv = *(const h8*)(wini + kk * 512 + lane * 8);
            cv = __builtin_amdgcn_mfma_f32_32x32x16_f16(av, bv, cv, 0, 0, 0);
        }
        {
            h8 av = {};
            if (hi == 0) {
                const float4 z0 = *(const float4*)(zr + 96);
                av[0] = (f16)z0.x; av[1] = (f16)z0.y;
                av[2] = (f16)z0.z; av[3] = (f16)z0.w;
                av[4] = (f16)1.0f;       // k=100 -> bias
            }
            h8 bv = *(const h8*)(wini + 6 * 512 + lane * 8);
            cv = __builtin_amdgcn_mfma_f32_32x32x16_f16(av, bv, cv, 0, 0, 0);
        }
        #pragma unroll
        for (int r = 0; r < 16; ++r) {
            int row = (r & 3) + 8 * (r >> 2) + 4 * hi;
            *(f16*)(hb0 + ((row * 128 + (G * 32 + lrow) * 2) ^ ((row & 7) << 4)))
                = (f16)cv[r];
        }
    }

    // plant state: every lane holds row (rowbase + lrow)
    float4 s0 = ((const float4*)init_state)[rowbase + lrow];
    float sx = s0.x, sy = s0.y, sz = s0.z, sw = s0.w;
    const float bc0 = b_ctrl[0], bc1 = b_ctrl[1];
    float4* op = (float4*)out + (size_t)(rowbase + lrow) * SEQ_LEN;

    __syncthreads();   // weights + h0 visible

#define MM(KK, AF)                                                             \
    { h8 bI = *(const h8*)(wm + ((G * 4 + 0) * 5 + (KK)) * 1024 + lane16);     \
      h8 bF = *(const h8*)(wm + ((G * 4 + 1) * 5 + (KK)) * 1024 + lane16);     \
      h8 bG = *(const h8*)(wm + ((G * 4 + 2) * 5 + (KK)) * 1024 + lane16);     \
      h8 bO = *(const h8*)(wm + ((G * 4 + 3) * 5 + (KK)) * 1024 + lane16);     \
      aI  = __builtin_amdgcn_mfma_f32_32x32x16_f16(AF, bI, aI,  0, 0, 0);      \
      aF  = __builtin_amdgcn_mfma_f32_32x32x16_f16(AF, bF, aF,  0, 0, 0);      \
      aGt = __builtin_amdgcn_mfma_f32_32x32x16_f16(AF, bG, aGt, 0, 0, 0);      \
      aO  = __builtin_amdgcn_mfma_f32_32x32x16_f16(AF, bO, aO,  0, 0, 0); }

#define STEP(HBP, HBQ, T) do {                                                 \
    h8 af0 = *(const h8*)((HBP) + ((lrow * 128 +  0 + hi * 16) ^ ((lrow & 7) << 4))); \
    h8 af1 = *(const h8*)((HBP) + ((lrow * 128 + 32 + hi * 16) ^ ((lrow & 7) << 4))); \
    h8 af2 = *(const h8*)((HBP) + ((lrow * 128 + 64 + hi * 16) ^ ((lrow & 7) << 4))); \
    h8 af3 = *(const h8*)((HBP) + ((lrow * 128 + 96 + hi * 16) ^ ((lrow & 7) << 4))); \
    h8 af4 = {};                                                               \
    if (hi == 0) {                                                             \
        af4[0] = (f16)sx; af4[1] = (f16)sy;                                    \
        af4[2] = (f16)sz; af4[3] = (f16)sw;                                    \
        af4[4] = (f16)1.0f;                                                    \
    }                                                                          \
    fx16 aI = {}, aF = {}, aGt = {}, aO = {};                                  \
    MM(0, af0) MM(1, af1) MM(2, af2) MM(3, af3) MM(4, af4)                     \
    _Pragma("unroll")                                                          \
    for (int r = 0; r < 16; ++r) {                                             \
        float eI = ex2(aI[r]);  float ig = rcpf(1.0f + eI);                    \
        float eF = ex2(aF[r]);  float fg = rcpf(1.0f + eF);                    \
        float eG = ex2(aGt[r]); float gg = (1.0f - eG) * rcpf(1.0f + eG);      \
        float eO = ex2(aO[r]);  float og = rcpf(1.0f + eO);                    \
        float cc = fmaf(fg, cv[r], ig * gg);                                   \
        cv[r] = cc;                                                            \
        float eC = ex2(cc * N2LOG2E);                                          \
        float hn = og * (1.0f - eC) * rcpf(1.0f + eC);                         \
        int row = (r & 3) + 8 * (r >> 2) + 4 * hi;                             \
        *(f16*)((HBQ) + ((row * 128 + (G * 32 + lrow) * 2) ^ ((row & 7) << 4)))\
            = (f16)hn;                                                         \
    }                                                                          \
    __syncthreads();                                                           \
    h8 pv = {}, qv = {};                                                       \
    _Pragma("unroll")                                                          \
    for (int jj = 0; jj < 4; ++jj) {                                           \
        h8 hv = *(const h8*)((HBQ) + ((lrow * 128 + hi * 64 + jj * 16)         \
                                      ^ ((lrow & 7) << 4)));                   \
        h8 w0 = *(const h8*)(wc + hi * 64 + jj * 16);                          \
        h8 w1 = *(const h8*)(wc + 128 + hi * 64 + jj * 16);                    \
        pv = __builtin_elementwise_fma(hv, w0, pv);                            \
        qv = __builtin_elementwise_fma(hv, w1, qv);                            \
    }                                                                          \
    float pp = hsum8(pv), qq = hsum8(qv);                                      \
    float ped = bc0 + pp + __shfl_xor(pp, 32);                                 \
    float str = bc1 + qq + __shfl_xor(qq, 32);                                 \
    float beta = fminf(0.5f, fmaxf(-0.5f, str));                               \
    float v1   = fminf(10.0f, fmaxf(0.0f, fmaf(ped, DT, sw)));                 \
    float cpsi = __cosf(sz);                                                   \
    float spsi = __sinf(sz);                                                   \
    float tb   = __sinf(beta) * rcpf(__cosf(beta));                            \
    float psid = fminf(1.57f, fmaxf(-1.57f, sw * tb * 0.4f));                  \
    sx = fmaf(v1 * cpsi, DT, sx);                                              \
    sy = fmaf(v1 * spsi, DT, sy);                                              \
    sz = fmaf(psid, DT, sz);                                                   \
    sw = v1;                                                                   \
    if (G == 0 && lane < 32) op[(T)] = make_float4(sx, sy, sz, sw);            \
} while (0)

    #pragma unroll 1
    for (int t2 = 0; t2 < SEQ_LEN; t2 += 2) {
        STEP(hb0, hb1, t2);
        STEP(hb1, hb0, t2 + 1);
    }
#undef STEP
#undef MM
}

extern "C" void kernel_launch(void* const* d_in, const int* in_sizes, int n_in,
                              void* d_out, int out_size, void* d_ws, size_t ws_size,
                              hipStream_t stream) {
    const float* z          = (const float*)d_in[0];
    const float* init_state = (const float*)d_in[1];
    const float* W_emb      = (const float*)d_in[2];
    const float* b_emb      = (const float*)d_in[3];
    const float* W_ih       = (const float*)d_in[4];
    const float* W_hh       = (const float*)d_in[5];
    const float* b_ih       = (const float*)d_in[6];
    const float* b_hh       = (const float*)d_in[7];
    const float* W_ctrl     = (const float*)d_in[8];
    const float* b_ctrl     = (const float*)d_in[9];
    const float* W_init     = (const float*)d_in[10];
    const float* b_init     = (const float*)d_in[11];
    float* out = (float*)d_out;
    f16*   wsh = (f16*)d_ws;

    prep_kernel<<<1, 256, 0, stream>>>(W_emb, b_emb, W_ih, b_ih, b_hh, W_hh,
                                       W_ctrl, W_init, b_init, wsh);
    rollout_kernel<<<BATCH / 128, 512, 0, stream>>>(z, init_state, b_ctrl,
                                                    wsh, out);
}

// Round 7
// 598.785 us; speedup vs baseline: 14.1043x; 1.2199x over previous
//
#include <hip/hip_runtime.h>

typedef _Float16 f16;
typedef _Float16 h8   __attribute__((ext_vector_type(8)));
typedef float    fx16 __attribute__((ext_vector_type(16)));
typedef unsigned int u32x4 __attribute__((ext_vector_type(4)));

#define BATCH   262144
#define SEQ_LEN 30
#define DT      0.03f
#define N2LOG2E (-2.8853900817779268f)

__device__ __forceinline__ float rcpf(float x) { return __builtin_amdgcn_rcpf(x); }
__device__ __forceinline__ float ex2(float x)  { return __builtin_amdgcn_exp2f(x); }
__device__ __forceinline__ float hsum8(h8 v) {
    _Float16 a0 = (_Float16)(v[0] + v[4]);
    _Float16 a1 = (_Float16)(v[1] + v[5]);
    _Float16 a2 = (_Float16)(v[2] + v[6]);
    _Float16 a3 = (_Float16)(v[3] + v[7]);
    return ((float)(_Float16)(a0 + a2)) + ((float)(_Float16)(a1 + a3));
}

// wsh image (f16 units):
//  [0, 20480)     WMAIN frag ((G*4+g)*5+kk) x 64 lanes x 8:
//                 n = g*64 + G*32 + (l&31), k = kk*16 + (l>>5)*8 + e
//                 k<64: W_hh[n][k]*sc; 64-67: Weff[n][k-64]*sc; 68: beff[n]*sc; else 0
//                 sc = -log2(e) for gates i,f,o; -2*log2(e) for gate g
//  [20480, 27648) WINIT frag (G*7+kk2) x 64 x 8 (unscaled)
//  [27648, 27776) WCTRL
__global__ void prep_kernel(const float* __restrict__ W_emb,
                            const float* __restrict__ b_emb,
                            const float* __restrict__ W_ih,
                            const float* __restrict__ b_ih,
                            const float* __restrict__ b_hh,
                            const float* __restrict__ W_hh,
                            const float* __restrict__ W_ctrl,
                            const float* __restrict__ W_init,
                            const float* __restrict__ b_init,
                            f16* __restrict__ wsh) {
    __shared__ float weff_s[256][4];
    __shared__ float beff_s[256];
    {
        int r = threadIdx.x;
        float a0 = 0.f, a1 = 0.f, a2 = 0.f, a3 = 0.f;
        float bb = b_ih[r] + b_hh[r];
        for (int k = 0; k < 64; ++k) {
            float w = W_ih[r * 64 + k];
            a0 = fmaf(w, W_emb[k * 4 + 0], a0);
            a1 = fmaf(w, W_emb[k * 4 + 1], a1);
            a2 = fmaf(w, W_emb[k * 4 + 2], a2);
            a3 = fmaf(w, W_emb[k * 4 + 3], a3);
            bb = fmaf(w, b_emb[k], bb);
        }
        weff_s[r][0] = a0; weff_s[r][1] = a1;
        weff_s[r][2] = a2; weff_s[r][3] = a3;
        beff_s[r] = bb;
    }
    __syncthreads();
    for (int idx = threadIdx.x; idx < 20480; idx += 256) {
        int frag = idx >> 9, rem = idx & 511;
        int l = rem >> 3, e = rem & 7;
        int G  = frag / 20;
        int g  = (frag / 5) & 3;
        int kk = frag % 5;
        int n = g * 64 + G * 32 + (l & 31);
        int k = kk * 16 + (l >> 5) * 8 + e;
        float sc = (g == 2) ? -2.8853900817779268f : -1.4426950408889634f;
        float v;
        if      (k < 64)  v = W_hh[n * 64 + k];
        else if (k < 68)  v = weff_s[n][k - 64];
        else if (k == 68) v = beff_s[n];
        else              v = 0.0f;
        wsh[idx] = (f16)(v * sc);
    }
    for (int idx = threadIdx.x; idx < 7168; idx += 256) {
        int fr = idx >> 9, rem = idx & 511;
        int l = rem >> 3, e = rem & 7;
        int G = fr / 7, kk2 = fr % 7;
        int n = G * 32 + (l & 31);
        int k = kk2 * 16 + (l >> 5) * 8 + e;
        float v = (k < 100) ? W_init[n * 100 + k]
                            : ((k == 100) ? b_init[n] : 0.0f);
        wsh[20480 + idx] = (f16)v;
    }
    if (threadIdx.x < 128) wsh[27648 + threadIdx.x] = (f16)W_ctrl[threadIdx.x];
}

__launch_bounds__(512, 4)
__global__ void rollout_kernel(const float* __restrict__ z,
                               const float* __restrict__ init_state,
                               const float* __restrict__ b_ctrl,
                               const f16* __restrict__ wsh,
                               float* __restrict__ out) {
    __shared__ __align__(16) f16 wmain[20480];       // 40 KB
    __shared__ __align__(16) f16 htile[2][4][2048];  // ping-pong, 32 KB
    __shared__ __align__(16) f16 wctrl[128];

    const int tid  = threadIdx.x;
    const int lane = tid & 63;
    const int wv   = tid >> 6;
    const int team = wv >> 1;
    const int G    = wv & 1;
    const int lrow = lane & 31;
    const int hi   = lane >> 5;
    const int rowbase = blockIdx.x * 128 + team * 32;
    const int lane16  = lane * 16;

    {   // stage weights
        const uint4* src = (const uint4*)wsh;
        uint4* dst = (uint4*)wmain;
        for (int i = tid; i < 2560; i += 512) dst[i] = src[i];
        if (tid < 16) ((uint4*)wctrl)[tid] = ((const uint4*)(wsh + 27648))[tid];
    }

    char* hb       = (char*)&htile[0][team][0];   // +16384 -> buffer 1
    const char* wm = (const char*)wmain;
    const char* wc = (const char*)wctrl;

    // precomputed swizzled LDS byte offsets (loop-invariant)
    const unsigned swz  = (unsigned)((lrow & 7) << 4);
    const unsigned col2 = (unsigned)((G * 32 + lrow) * 2);
    u32x4 rav, rcv, wbv;
    #pragma unroll
    for (int q = 0; q < 4; ++q) {
        rav[q] = (unsigned)(lrow * 128) + ((unsigned)(q * 32 + hi * 16) ^ swz);
        rcv[q] = (unsigned)(lrow * 128) + ((unsigned)(hi * 64 + q * 16) ^ swz);
        wbv[q] = (unsigned)(hi * 512) + (col2 ^ (unsigned)((q + 4 * hi) << 4));
    }

    // ---- init: c0 = h0 = z @ W_init^T + b_init (K=112, bias at k=100) ----
    fx16 cv = {};
    {
        const float* zr   = z + (size_t)(rowbase + lrow) * 100;
        const f16*   wini = wsh + 20480 + G * 7 * 512;
        #pragma unroll
        for (int kk = 0; kk < 6; ++kk) {
            const float4 z0 = *(const float4*)(zr + kk * 16 + hi * 8);
            const float4 z1 = *(const float4*)(zr + kk * 16 + hi * 8 + 4);
            h8 av;
            av[0] = (f16)z0.x; av[1] = (f16)z0.y; av[2] = (f16)z0.z; av[3] = (f16)z0.w;
            av[4] = (f16)z1.x; av[5] = (f16)z1.y; av[6] = (f16)z1.z; av[7] = (f16)z1.w;
            h8 bv = *(const h8*)(wini + kk * 512 + lane * 8);
            cv = __builtin_amdgcn_mfma_f32_32x32x16_f16(av, bv, cv, 0, 0, 0);
        }
        {
            h8 av = {};
            if (hi == 0) {
                const float4 z0 = *(const float4*)(zr + 96);
                av[0] = (f16)z0.x; av[1] = (f16)z0.y;
                av[2] = (f16)z0.z; av[3] = (f16)z0.w;
                av[4] = (f16)1.0f;       // k=100 -> bias
            }
            h8 bv = *(const h8*)(wini + 6 * 512 + lane * 8);
            cv = __builtin_amdgcn_mfma_f32_32x32x16_f16(av, bv, cv, 0, 0, 0);
        }
        #pragma unroll
        for (int r = 0; r < 16; ++r)
            *(f16*)(hb + wbv[r & 3] + ((r >> 2) * 1024 + (r & 3) * 128))
                = (f16)cv[r];
    }

    // plant state: every lane holds row (rowbase + lrow)
    float4 s0 = ((const float4*)init_state)[rowbase + lrow];
    float sx = s0.x, sy = s0.y, sz = s0.z, sw = s0.w;
    const float bc0 = b_ctrl[0], bc1 = b_ctrl[1];
    float4* op = (float4*)out + (size_t)(rowbase + lrow) * SEQ_LEN;

    __syncthreads();   // weights + h0 visible

#define MM(KK, AF)                                                             \
    { h8 bI = *(const h8*)(wm + ((G * 4 + 0) * 5 + (KK)) * 1024 + lane16);     \
      h8 bF = *(const h8*)(wm + ((G * 4 + 1) * 5 + (KK)) * 1024 + lane16);     \
      h8 bG = *(const h8*)(wm + ((G * 4 + 2) * 5 + (KK)) * 1024 + lane16);     \
      h8 bO = *(const h8*)(wm + ((G * 4 + 3) * 5 + (KK)) * 1024 + lane16);     \
      aI  = __builtin_amdgcn_mfma_f32_32x32x16_f16(AF, bI, aI,  0, 0, 0);      \
      aF  = __builtin_amdgcn_mfma_f32_32x32x16_f16(AF, bF, aF,  0, 0, 0);      \
      aGt = __builtin_amdgcn_mfma_f32_32x32x16_f16(AF, bG, aGt, 0, 0, 0);      \
      aO  = __builtin_amdgcn_mfma_f32_32x32x16_f16(AF, bO, aO,  0, 0, 0); }

// POFS/QOFS are literal 0/16384 (ping-pong buffer byte offsets)
#define STEP(POFS, QOFS, T) do {                                               \
    h8 af0 = *(const h8*)(hb + (POFS) + rav[0]);                               \
    h8 af1 = *(const h8*)(hb + (POFS) + rav[1]);                               \
    h8 af2 = *(const h8*)(hb + (POFS) + rav[2]);                               \
    h8 af3 = *(const h8*)(hb + (POFS) + rav[3]);                               \
    h8 af4 = {};                                                               \
    if (hi == 0) {                                                             \
        af4[0] = (f16)sx; af4[1] = (f16)sy;                                    \
        af4[2] = (f16)sz; af4[3] = (f16)sw;                                    \
        af4[4] = (f16)1.0f;                                                    \
    }                                                                          \
    fx16 aI = {}, aF = {}, aGt = {}, aO = {};                                  \
    MM(0, af0) MM(1, af1) MM(2, af2) MM(3, af3) MM(4, af4)                     \
    _Pragma("unroll")                                                          \
    for (int r = 0; r < 16; ++r) {                                             \
        float eI = ex2(aI[r]);                                                 \
        float eF = ex2(aF[r]);                                                 \
        float eG = ex2(aGt[r]);                                                \
        float eO = ex2(aO[r]);                                                 \
        float pF = 1.0f + eF;                                                  \
        float P  = (1.0f + eI) * (1.0f + eG);                                  \
        float num = fmaf(cv[r], P, (1.0f - eG) * pF);                          \
        float cc  = num * rcpf(pF * P);                                        \
        cv[r] = cc;                                                            \
        float eC = ex2(cc * N2LOG2E);                                          \
        float hn = (1.0f - eC) * rcpf((1.0f + eO) * (1.0f + eC));              \
        *(f16*)(hb + (QOFS) + wbv[r & 3] + ((r >> 2) * 1024 + (r & 3) * 128))  \
            = (f16)hn;                                                         \
    }                                                                          \
    __syncthreads();                                                           \
    h8 pv = {}, qv = {};                                                       \
    _Pragma("unroll")                                                          \
    for (int jj = 0; jj < 4; ++jj) {                                           \
        h8 hv = *(const h8*)(hb + (QOFS) + rcv[jj]);                           \
        h8 w0 = *(const h8*)(wc + hi * 64 + jj * 16);                          \
        h8 w1 = *(const h8*)(wc + 128 + hi * 64 + jj * 16);                    \
        pv = __builtin_elementwise_fma(hv, w0, pv);                            \
        qv = __builtin_elementwise_fma(hv, w1, qv);                            \
    }                                                                          \
    float pp = hsum8(pv), qq = hsum8(qv);                                      \
    float ped = bc0 + pp + __shfl_xor(pp, 32);                                 \
    float str = bc1 + qq + __shfl_xor(qq, 32);                                 \
    float beta = fminf(0.5f, fmaxf(-0.5f, str));                               \
    float v1   = fminf(10.0f, fmaxf(0.0f, fmaf(ped, DT, sw)));                 \
    float cpsi = __cosf(sz);                                                   \
    float spsi = __sinf(sz);                                                   \
    float b2   = beta * beta;                                                  \
    float tb   = beta * fmaf(b2, fmaf(b2, fmaf(b2, 0.05396825397f,             \
                         0.13333333333f), 0.33333333333f), 1.0f);              \
    float psid = fminf(1.57f, fmaxf(-1.57f, sw * tb * 0.4f));                  \
    sx = fmaf(v1 * cpsi, DT, sx);                                              \
    sy = fmaf(v1 * spsi, DT, sy);                                              \
    sz = fmaf(psid, DT, sz);                                                   \
    sw = v1;                                                                   \
    if (G == 0 && lane < 32) op[(T)] = make_float4(sx, sy, sz, sw);            \
} while (0)

    #pragma unroll 1
    for (int t2 = 0; t2 < SEQ_LEN; t2 += 2) {
        STEP(0, 16384, t2);
        STEP(16384, 0, t2 + 1);
    }
#undef STEP
#undef MM
}

extern "C" void kernel_launch(void* const* d_in, const int* in_sizes, int n_in,
                              void* d_out, int out_size, void* d_ws, size_t ws_size,
                              hipStream_t stream) {
    const float* z          = (const float*)d_in[0];
    const float* init_state = (const float*)d_in[1];
    const float* W_emb      = (const float*)d_in[2];
    const float* b_emb      = (const float*)d_in[3];
    const float* W_ih       = (const float*)d_in[4];
    const float* W_hh       = (const float*)d_in[5];
    const float* b_ih       = (const float*)d_in[6];
    const float* b_hh       = (const float*)d_in[7];
    const float* W_ctrl     = (const float*)d_in[8];
    const float* b_ctrl     = (const float*)d_in[9];
    const float* W_init     = (const float*)d_in[10];
    const float* b_init     = (const float*)d_in[11];
    float* out = (float*)d_out;
    f16*   wsh = (f16*)d_ws;

    prep_kernel<<<1, 256, 0, stream>>>(W_emb, b_emb, W_ih, b_ih, b_hh, W_hh,
                                       W_ctrl, W_init, b_init, wsh);
    rollout_kernel<<<BATCH / 128, 512, 0, stream>>>(z, init_state, b_ctrl,
                                                    wsh, out);
}

// Round 8
// 587.534 us; speedup vs baseline: 14.3744x; 1.0191x over previous
//
#include <hip/hip_runtime.h>

typedef _Float16 f16;
typedef _Float16 h8   __attribute__((ext_vector_type(8)));
typedef float    fx16 __attribute__((ext_vector_type(16)));
typedef float    fl2  __attribute__((ext_vector_type(2)));
typedef unsigned int u32x4 __attribute__((ext_vector_type(4)));

#define BATCH   262144
#define SEQ_LEN 30
#define DT      0.03f
#define N2LOG2E (-2.8853900817779268f)

__device__ __forceinline__ float rcpf(float x) { return __builtin_amdgcn_rcpf(x); }
__device__ __forceinline__ float ex2(float x)  { return __builtin_amdgcn_exp2f(x); }
__device__ __forceinline__ float hsum8(h8 v) {
    _Float16 a0 = (_Float16)(v[0] + v[4]);
    _Float16 a1 = (_Float16)(v[1] + v[5]);
    _Float16 a2 = (_Float16)(v[2] + v[6]);
    _Float16 a3 = (_Float16)(v[3] + v[7]);
    return ((float)(_Float16)(a0 + a2)) + ((float)(_Float16)(a1 + a3));
}

// wsh image (f16 units):
//  [0, 20480)     WMAIN frag ((G*4+g)*5+kk) x 64 lanes x 8:
//                 n = g*64 + G*32 + (l&31), k = kk*16 + (l>>5)*8 + e
//                 k<64: W_hh[n][k]*sc; 64-67: Weff[n][k-64]*sc; 68: beff[n]*sc; else 0
//                 sc = -log2(e) for gates i,f,o; -2*log2(e) for gate g
//  [20480, 27648) WINIT frag (G*7+kk2) x 64 x 8 (unscaled)
//  [27648, 27776) WCTRL
__global__ void prep_kernel(const float* __restrict__ W_emb,
                            const float* __restrict__ b_emb,
                            const float* __restrict__ W_ih,
                            const float* __restrict__ b_ih,
                            const float* __restrict__ b_hh,
                            const float* __restrict__ W_hh,
                            const float* __restrict__ W_ctrl,
                            const float* __restrict__ W_init,
                            const float* __restrict__ b_init,
                            f16* __restrict__ wsh) {
    __shared__ float weff_s[256][4];
    __shared__ float beff_s[256];
    {
        int r = threadIdx.x;
        float a0 = 0.f, a1 = 0.f, a2 = 0.f, a3 = 0.f;
        float bb = b_ih[r] + b_hh[r];
        for (int k = 0; k < 64; ++k) {
            float w = W_ih[r * 64 + k];
            a0 = fmaf(w, W_emb[k * 4 + 0], a0);
            a1 = fmaf(w, W_emb[k * 4 + 1], a1);
            a2 = fmaf(w, W_emb[k * 4 + 2], a2);
            a3 = fmaf(w, W_emb[k * 4 + 3], a3);
            bb = fmaf(w, b_emb[k], bb);
        }
        weff_s[r][0] = a0; weff_s[r][1] = a1;
        weff_s[r][2] = a2; weff_s[r][3] = a3;
        beff_s[r] = bb;
    }
    __syncthreads();
    for (int idx = threadIdx.x; idx < 20480; idx += 256) {
        int frag = idx >> 9, rem = idx & 511;
        int l = rem >> 3, e = rem & 7;
        int G  = frag / 20;
        int g  = (frag / 5) & 3;
        int kk = frag % 5;
        int n = g * 64 + G * 32 + (l & 31);
        int k = kk * 16 + (l >> 5) * 8 + e;
        float sc = (g == 2) ? -2.8853900817779268f : -1.4426950408889634f;
        float v;
        if      (k < 64)  v = W_hh[n * 64 + k];
        else if (k < 68)  v = weff_s[n][k - 64];
        else if (k == 68) v = beff_s[n];
        else              v = 0.0f;
        wsh[idx] = (f16)(v * sc);
    }
    for (int idx = threadIdx.x; idx < 7168; idx += 256) {
        int fr = idx >> 9, rem = idx & 511;
        int l = rem >> 3, e = rem & 7;
        int G = fr / 7, kk2 = fr % 7;
        int n = G * 32 + (l & 31);
        int k = kk2 * 16 + (l >> 5) * 8 + e;
        float v = (k < 100) ? W_init[n * 100 + k]
                            : ((k == 100) ? b_init[n] : 0.0f);
        wsh[20480 + idx] = (f16)v;
    }
    if (threadIdx.x < 128) wsh[27648 + threadIdx.x] = (f16)W_ctrl[threadIdx.x];
}

__launch_bounds__(512, 4)
__global__ void rollout_kernel(const float* __restrict__ z,
                               const float* __restrict__ init_state,
                               const float* __restrict__ b_ctrl,
                               const f16* __restrict__ wsh,
                               float* __restrict__ out) {
    __shared__ __align__(16) f16 wmain[20480];       // 40 KB
    __shared__ __align__(16) f16 htile[2][4][2048];  // ping-pong, 32 KB
    __shared__ __align__(16) f16 wctrl[128];

    const int tid  = threadIdx.x;
    const int lane = tid & 63;
    const int wv   = tid >> 6;
    const int team = wv >> 1;
    const int G    = wv & 1;
    const int lrow = lane & 31;
    const int hi   = lane >> 5;
    const int rowbase = blockIdx.x * 128 + team * 32;
    const int lane16  = lane * 16;

    {   // stage weights
        const uint4* src = (const uint4*)wsh;
        uint4* dst = (uint4*)wmain;
        for (int i = tid; i < 2560; i += 512) dst[i] = src[i];
        if (tid < 16) ((uint4*)wctrl)[tid] = ((const uint4*)(wsh + 27648))[tid];
    }

    char* hb       = (char*)&htile[0][team][0];   // +16384 -> buffer 1
    const char* wm = (const char*)wmain;
    const char* wc = (const char*)wctrl;

    // precomputed swizzled LDS byte offsets (loop-invariant)
    const unsigned swz  = (unsigned)((lrow & 7) << 4);
    const unsigned col2 = (unsigned)((G * 32 + lrow) * 2);
    u32x4 rav, rcv, wbv;
    #pragma unroll
    for (int q = 0; q < 4; ++q) {
        rav[q] = (unsigned)(lrow * 128) + ((unsigned)(q * 32 + hi * 16) ^ swz);
        rcv[q] = (unsigned)(lrow * 128) + ((unsigned)(hi * 64 + q * 16) ^ swz);
        wbv[q] = (unsigned)(hi * 512) + (col2 ^ (unsigned)((q + 4 * hi) << 4));
    }

    // ---- init: c0 = h0 = z @ W_init^T + b_init (K=112, bias at k=100) ----
    fx16 cv = {};
    {
        const float* zr   = z + (size_t)(rowbase + lrow) * 100;
        const f16*   wini = wsh + 20480 + G * 7 * 512;
        #pragma unroll
        for (int kk = 0; kk < 6; ++kk) {
            const float4 z0 = *(const float4*)(zr + kk * 16 + hi * 8);
            const float4 z1 = *(const float4*)(zr + kk * 16 + hi * 8 + 4);
            h8 av;
            av[0] = (f16)z0.x; av[1] = (f16)z0.y; av[2] = (f16)z0.z; av[3] = (f16)z0.w;
            av[4] = (f16)z1.x; av[5] = (f16)z1.y; av[6] = (f16)z1.z; av[7] = (f16)z1.w;
            h8 bv = *(const h8*)(wini + kk * 512 + lane * 8);
            cv = __builtin_amdgcn_mfma_f32_32x32x16_f16(av, bv, cv, 0, 0, 0);
        }
        {
            h8 av = {};
            if (hi == 0) {
                const float4 z0 = *(const float4*)(zr + 96);
                av[0] = (f16)z0.x; av[1] = (f16)z0.y;
                av[2] = (f16)z0.z; av[3] = (f16)z0.w;
                av[4] = (f16)1.0f;       // k=100 -> bias
            }
            h8 bv = *(const h8*)(wini + 6 * 512 + lane * 8);
            cv = __builtin_amdgcn_mfma_f32_32x32x16_f16(av, bv, cv, 0, 0, 0);
        }
        #pragma unroll
        for (int r = 0; r < 16; ++r)
            *(f16*)(hb + wbv[r & 3] + ((r >> 2) * 1024 + (r & 3) * 128))
                = (f16)cv[r];
    }

    // plant state: every lane holds row (rowbase + lrow)
    float4 s0 = ((const float4*)init_state)[rowbase + lrow];
    float sx = s0.x, sy = s0.y, sz = s0.z, sw = s0.w;
    const float bc0 = b_ctrl[0], bc1 = b_ctrl[1];
    float4* op = (float4*)out + (size_t)(rowbase + lrow) * SEQ_LEN;

    __syncthreads();   // weights + h0 visible

#define MM(KK, AF)                                                             \
    { h8 bI = *(const h8*)(wm + ((G * 4 + 0) * 5 + (KK)) * 1024 + lane16);     \
      h8 bF = *(const h8*)(wm + ((G * 4 + 1) * 5 + (KK)) * 1024 + lane16);     \
      h8 bG = *(const h8*)(wm + ((G * 4 + 2) * 5 + (KK)) * 1024 + lane16);     \
      h8 bO = *(const h8*)(wm + ((G * 4 + 3) * 5 + (KK)) * 1024 + lane16);     \
      aI  = __builtin_amdgcn_mfma_f32_32x32x16_f16(AF, bI, aI,  0, 0, 0);      \
      aF  = __builtin_amdgcn_mfma_f32_32x32x16_f16(AF, bF, aF,  0, 0, 0);      \
      aGt = __builtin_amdgcn_mfma_f32_32x32x16_f16(AF, bG, aGt, 0, 0, 0);      \
      aO  = __builtin_amdgcn_mfma_f32_32x32x16_f16(AF, bO, aO,  0, 0, 0); }

// POFS/QOFS are literal 0/16384 (ping-pong buffer byte offsets)
#define STEP(POFS, QOFS, T) do {                                               \
    h8 af0 = *(const h8*)(hb + (POFS) + rav[0]);                               \
    h8 af1 = *(const h8*)(hb + (POFS) + rav[1]);                               \
    h8 af2 = *(const h8*)(hb + (POFS) + rav[2]);                               \
    h8 af3 = *(const h8*)(hb + (POFS) + rav[3]);                               \
    h8 af4 = {};                                                               \
    if (hi == 0) {                                                             \
        af4[0] = (f16)sx; af4[1] = (f16)sy;                                    \
        af4[2] = (f16)sz; af4[3] = (f16)sw;                                    \
        af4[4] = (f16)1.0f;                                                    \
    }                                                                          \
    fx16 aI = {}, aF = {}, aGt = {}, aO = {};                                  \
    MM(0, af0) MM(1, af1) MM(2, af2) MM(3, af3) MM(4, af4)                     \
    _Pragma("unroll")                                                          \
    for (int r2 = 0; r2 < 8; ++r2) {                                           \
        const int r = 2 * r2;                                                  \
        fl2 eI = { ex2(aI[r]),  ex2(aI[r + 1])  };                             \
        fl2 eF = { ex2(aF[r]),  ex2(aF[r + 1])  };                             \
        fl2 eG = { ex2(aGt[r]), ex2(aGt[r + 1]) };                             \
        fl2 eO = { ex2(aO[r]),  ex2(aO[r + 1])  };                             \
        fl2 pF  = 1.0f + eF;                                                   \
        fl2 P   = (1.0f + eI) * (1.0f + eG);                                   \
        fl2 cvp = { cv[r], cv[r + 1] };                                        \
        fl2 num = __builtin_elementwise_fma(cvp, P, (1.0f - eG) * pF);         \
        fl2 dP  = pF * P;                                                      \
        fl2 rdP = { rcpf(dP[0]), rcpf(dP[1]) };                                \
        fl2 cc  = num * rdP;                                                   \
        cv[r] = cc[0]; cv[r + 1] = cc[1];                                      \
        fl2 ccn = cc * N2LOG2E;                                                \
        fl2 eC  = { ex2(ccn[0]), ex2(ccn[1]) };                                \
        fl2 den = (1.0f + eO) * (1.0f + eC);                                   \
        fl2 rdn = { rcpf(den[0]), rcpf(den[1]) };                              \
        fl2 hn  = (1.0f - eC) * rdn;                                           \
        *(f16*)(hb + (QOFS) + wbv[r & 3] + ((r >> 2) * 1024 + (r & 3) * 128))  \
            = (f16)hn[0];                                                      \
        *(f16*)(hb + (QOFS) + wbv[(r + 1) & 3]                                 \
                + (((r + 1) >> 2) * 1024 + ((r + 1) & 3) * 128))               \
            = (f16)hn[1];                                                      \
    }                                                                          \
    __syncthreads();                                                           \
    h8 pv = {}, qv = {};                                                       \
    _Pragma("unroll")                                                          \
    for (int jj = 0; jj < 4; ++jj) {                                           \
        h8 hv = *(const h8*)(hb + (QOFS) + rcv[jj]);                           \
        h8 w0 = *(const h8*)(wc + hi * 64 + jj * 16);                          \
        h8 w1 = *(const h8*)(wc + 128 + hi * 64 + jj * 16);                    \
        pv = __builtin_elementwise_fma(hv, w0, pv);                            \
        qv = __builtin_elementwise_fma(hv, w1, qv);                            \
    }                                                                          \
    float pp = hsum8(pv), qq = hsum8(qv);                                      \
    float ped = bc0 + pp + __shfl_xor(pp, 32);                                 \
    float str = bc1 + qq + __shfl_xor(qq, 32);                                 \
    float beta = fminf(0.5f, fmaxf(-0.5f, str));                               \
    float v1   = fminf(10.0f, fmaxf(0.0f, fmaf(ped, DT, sw)));                 \
    float cpsi = __cosf(sz);                                                   \
    float spsi = __sinf(sz);                                                   \
    float b2   = beta * beta;                                                  \
    float tb   = beta * fmaf(b2, fmaf(b2, fmaf(b2, 0.05396825397f,             \
                         0.13333333333f), 0.33333333333f), 1.0f);              \
    float psid = fminf(1.57f, fmaxf(-1.57f, sw * tb * 0.4f));                  \
    sx = fmaf(v1 * cpsi, DT, sx);                                              \
    sy = fmaf(v1 * spsi, DT, sy);                                              \
    sz = fmaf(psid, DT, sz);                                                   \
    sw = v1;                                                                   \
    if (G == 0 && lane < 32) op[(T)] = make_float4(sx, sy, sz, sw);            \
} while (0)

    #pragma unroll 1
    for (int t2 = 0; t2 < SEQ_LEN; t2 += 2) {
        STEP(0, 16384, t2);
        STEP(16384, 0, t2 + 1);
    }
#undef STEP
#undef MM
}

extern "C" void kernel_launch(void* const* d_in, const int* in_sizes, int n_in,
                              void* d_out, int out_size, void* d_ws, size_t ws_size,
                              hipStream_t stream) {
    const float* z          = (const float*)d_in[0];
    const float* init_state = (const float*)d_in[1];
    const float* W_emb      = (const float*)d_in[2];
    const float* b_emb      = (const float*)d_in[3];
    const float* W_ih       = (const float*)d_in[4];
    const float* W_hh       = (const float*)d_in[5];
    const float* b_ih       = (const float*)d_in[6];
    const float* b_hh       = (const float*)d_in[7];
    const float* W_ctrl     = (const float*)d_in[8];
    const float* b_ctrl     = (const float*)d_in[9];
    const float* W_init     = (const float*)d_in[10];
    const float* b_init     = (const float*)d_in[11];
    float* out = (float*)d_out;
    f16*   wsh = (f16*)d_ws;

    prep_kernel<<<1, 256, 0, stream>>>(W_emb, b_emb, W_ih, b_ih, b_hh, W_hh,
                                       W_ctrl, W_init, b_init, wsh);
    rollout_kernel<<<BATCH / 128, 512, 0, stream>>>(z, init_state, b_ctrl,
                                                    wsh, out);
}